// Round 2
// 575.021 us; speedup vs baseline: 1.0023x; 1.0023x over previous
//
#include <hip/hip_runtime.h>

// O(2) full tensor product:
//   input1: (2048, 448)  irreps [(64,m=0),(64,m=1),(64,m=2),(64,m=3)]
//   input2: (2048, 160)  irreps [(32,m=0),(32,m=1),(32,m=2)]
//   output: (2048, 71680) — 20 CG-path chunks, sorted by (m_out, -parity)
//
// Write-BW-bound: 587 MB out vs 5 MB in. One block per batch row.
// This version vs previous (576 µs baseline):
//  * all output stores nontemporal (output never re-read; avoid L2
//    allocate+dirty-evict reorder on the 587 MB stream) — via native
//    ext_vector_type since the builtin rejects HIP_vector_type float4
//  * loop-invariant b-values register-cached once per chunk (v-index is
//    invariant across the r-unroll), cos/sin pairs fused (identical inputs),
//    vector chunks grouped by a-block so each a-fragment is read once.

#define R2F  0.70710678118654752440f
#define SQ2F 1.41421356237309504880f

constexpr int BATCH = 2048;
constexpr int DIM1  = 448;
constexpr int DIM2  = 160;
constexpr int ODIM  = 71680;   // per-batch output floats (17920 float4)

typedef float v4f __attribute__((ext_vector_type(4)));

__device__ __forceinline__ void ntst(v4f* p, float x, float y, float z, float w) {
    v4f v = {x, y, z, w};
    __builtin_nontemporal_store(v, p);
}

__global__ __launch_bounds__(256)
void tp_kernel(const float* __restrict__ g1, const float* __restrict__ g2,
               float* __restrict__ gout) {
    const int b  = blockIdx.x;
    const int t0 = threadIdx.x;

    __shared__ float s1[DIM1];
    __shared__ float s2[DIM2];
    {
        const float* x1 = g1 + (size_t)b * DIM1;
        const float* x2 = g2 + (size_t)b * DIM2;
        for (int i = t0; i < DIM1; i += 256) s1[i] = x1[i];
        for (int i = t0; i < DIM2; i += 256) s2[i] = x2[i];
    }
    __syncthreads();

    v4f* out = (v4f*)(gout + (size_t)b * ODIM);

    // index maps (invariant in the r-unroll):
    const int us  = t0 >> 3;             // scalar-chunk u base; +32 per r (r<2)
    const int vsc = (4 * t0) & 31;       // scalar-chunk v
    const int vs2 = 2 * vsc;             // scalar-chunk 2v
    const int uv  = t0 >> 4;             // vector-chunk u base; +16 per r (r<4)
    const int vv  = (2 * t0) & 31;       // vector-chunk v
    const int vv2 = 2 * vv;              // vector-chunk 2v

    // ---- (0x0 -> 0+) @ f4 0 : out[u*32+v] = a[u]*b[v], 512 f4
    {
        float b0 = s2[vsc], b1 = s2[vsc + 1], b2 = s2[vsc + 2], b3 = s2[vsc + 3];
        float a0 = s1[us], a1 = s1[us + 32];
        ntst(out + t0,       a0*b0, a0*b1, a0*b2, a0*b3);
        ntst(out + t0 + 256, a1*b0, a1*b1, a1*b2, a1*b3);
    }

    // ---- m=0 block of input1: sv chunks (0x1 ->1)@2560, (0x2 ->2)@7680
    {
        float av[4];
#pragma unroll
        for (int r = 0; r < 4; ++r) av[r] = s1[uv + 16 * r];
        float p0 = SQ2F * s2[32 + vv2], p1 = SQ2F * s2[33 + vv2],
              p2 = SQ2F * s2[34 + vv2], p3 = SQ2F * s2[35 + vv2];
        float q0 = SQ2F * s2[96 + vv2], q1 = SQ2F * s2[97 + vv2],
              q2 = SQ2F * s2[98 + vv2], q3 = SQ2F * s2[99 + vv2];
#pragma unroll
        for (int r = 0; r < 4; ++r) {
            float a = av[r];
            ntst(out + 2560 + t0 + 256 * r, a*p0, a*p1, a*p2, a*p3);
            ntst(out + 7680 + t0 + 256 * r, a*q0, a*q1, a*q2, a*q3);
        }
    }

    // ---- m=1 block of input1 (s1+64) -------------------------------------
    {
        float ca[4], sa[4];
#pragma unroll
        for (int r = 0; r < 4; ++r) {
            int j = 64 + 2 * (uv + 16 * r);
            ca[r] = s1[j]; sa[r] = s1[j + 1];
        }
        float b00 = SQ2F * s2[vv], b01 = SQ2F * s2[vv + 1];                  // m0
        float b10 = s2[32 + vv2], b11 = s2[33 + vv2],
              b12 = s2[34 + vv2], b13 = s2[35 + vv2];                        // m1
        float b20 = s2[96 + vv2], b21 = s2[97 + vv2],
              b22 = s2[98 + vv2], b23 = s2[99 + vv2];                        // m2
#pragma unroll
        for (int r = 0; r < 4; ++r) {
            float c = ca[r], s = sa[r];
            // vs (1x0 ->1) @3584
            ntst(out + 3584 + t0 + 256 * r, c*b00, s*b00, c*b01, s*b01);
            // diff (1x2 ->1, sgn=-1) @4608
            ntst(out + 4608 + t0 + 256 * r,
                 c*b20 + s*b21, c*b21 - s*b20,
                 c*b22 + s*b23, c*b23 - s*b22);
            // sum (1x1 ->2) @8704
            ntst(out + 8704 + t0 + 256 * r,
                 c*b10 - s*b11, s*b10 + c*b11,
                 c*b12 - s*b13, s*b12 + c*b13);
            // sum (1x2 ->3) @11776
            ntst(out + 11776 + t0 + 256 * r,
                 c*b20 - s*b21, s*b20 + c*b21,
                 c*b22 - s*b23, s*b22 + c*b23);
        }
        // fused cos/sin (1x1 -> 0+ @512, 0- @1536), scalar u-map, b = s2+32
        float e0 = s2[32 + vs2], e1 = s2[33 + vs2], e2 = s2[34 + vs2],
              e3 = s2[35 + vs2], e4 = s2[36 + vs2], e5 = s2[37 + vs2],
              e6 = s2[38 + vs2], e7 = s2[39 + vs2];
#pragma unroll
        for (int r = 0; r < 2; ++r) {
            int j = 64 + 2 * (us + 32 * r);
            float c = R2F * s1[j], s = R2F * s1[j + 1];
            ntst(out + 512 + t0 + 256 * r,
                 c*e0 + s*e1, c*e2 + s*e3, c*e4 + s*e5, c*e6 + s*e7);
            ntst(out + 1536 + t0 + 256 * r,
                 s*e0 - c*e1, s*e2 - c*e3, s*e4 - c*e5, s*e6 - c*e7);
        }
    }

    // ---- m=2 block of input1 (s1+192) ------------------------------------
    {
        float ca[4], sa[4];
#pragma unroll
        for (int r = 0; r < 4; ++r) {
            int j = 192 + 2 * (uv + 16 * r);
            ca[r] = s1[j]; sa[r] = s1[j + 1];
        }
        float b00 = SQ2F * s2[vv], b01 = SQ2F * s2[vv + 1];                  // m0
        float b10 = s2[32 + vv2], b11 = s2[33 + vv2],
              b12 = s2[34 + vv2], b13 = s2[35 + vv2];                        // m1
        float b20 = s2[96 + vv2], b21 = s2[97 + vv2],
              b22 = s2[98 + vv2], b23 = s2[99 + vv2];                        // m2
#pragma unroll
        for (int r = 0; r < 4; ++r) {
            float c = ca[r], s = sa[r];
            // diff (2x1 ->1, sgn=+1) @5632
            ntst(out + 5632 + t0 + 256 * r,
                 c*b10 + s*b11, s*b10 - c*b11,
                 c*b12 + s*b13, s*b12 - c*b13);
            // vs (2x0 ->2) @9728
            ntst(out + 9728 + t0 + 256 * r, c*b00, s*b00, c*b01, s*b01);
            // sum (2x1 ->3) @12800
            ntst(out + 12800 + t0 + 256 * r,
                 c*b10 - s*b11, s*b10 + c*b11,
                 c*b12 - s*b13, s*b12 + c*b13);
            // sum (2x2 ->4) @14848
            ntst(out + 14848 + t0 + 256 * r,
                 c*b20 - s*b21, s*b20 + c*b21,
                 c*b22 - s*b23, s*b22 + c*b23);
        }
        // fused cos/sin (2x2 -> 0+ @1024, 0- @2048), scalar u-map, b = s2+96
        float e0 = s2[96 + vs2], e1 = s2[97 + vs2], e2 = s2[98 + vs2],
              e3 = s2[99 + vs2], e4 = s2[100 + vs2], e5 = s2[101 + vs2],
              e6 = s2[102 + vs2], e7 = s2[103 + vs2];
#pragma unroll
        for (int r = 0; r < 2; ++r) {
            int j = 192 + 2 * (us + 32 * r);
            float c = R2F * s1[j], s = R2F * s1[j + 1];
            ntst(out + 1024 + t0 + 256 * r,
                 c*e0 + s*e1, c*e2 + s*e3, c*e4 + s*e5, c*e6 + s*e7);
            ntst(out + 2048 + t0 + 256 * r,
                 s*e0 - c*e1, s*e2 - c*e3, s*e4 - c*e5, s*e6 - c*e7);
        }
    }

    // ---- m=3 block of input1 (s1+320) ------------------------------------
    {
        float ca[4], sa[4];
#pragma unroll
        for (int r = 0; r < 4; ++r) {
            int j = 320 + 2 * (uv + 16 * r);
            ca[r] = s1[j]; sa[r] = s1[j + 1];
        }
        float b00 = SQ2F * s2[vv], b01 = SQ2F * s2[vv + 1];                  // m0
        float b10 = s2[32 + vv2], b11 = s2[33 + vv2],
              b12 = s2[34 + vv2], b13 = s2[35 + vv2];                        // m1
        float b20 = s2[96 + vv2], b21 = s2[97 + vv2],
              b22 = s2[98 + vv2], b23 = s2[99 + vv2];                        // m2
#pragma unroll
        for (int r = 0; r < 4; ++r) {
            float c = ca[r], s = sa[r];
            // diff (3x2 ->1, sgn=+1) @6656
            ntst(out + 6656 + t0 + 256 * r,
                 c*b20 + s*b21, s*b20 - c*b21,
                 c*b22 + s*b23, s*b22 - c*b23);
            // diff (3x1 ->2, sgn=+1) @10752
            ntst(out + 10752 + t0 + 256 * r,
                 c*b10 + s*b11, s*b10 - c*b11,
                 c*b12 + s*b13, s*b12 - c*b13);
            // vs (3x0 ->3) @13824
            ntst(out + 13824 + t0 + 256 * r, c*b00, s*b00, c*b01, s*b01);
            // sum (3x1 ->4) @15872
            ntst(out + 15872 + t0 + 256 * r,
                 c*b10 - s*b11, s*b10 + c*b11,
                 c*b12 - s*b13, s*b12 + c*b13);
            // sum (3x2 ->5) @16896
            ntst(out + 16896 + t0 + 256 * r,
                 c*b20 - s*b21, s*b20 + c*b21,
                 c*b22 - s*b23, s*b22 + c*b23);
        }
    }
}

extern "C" void kernel_launch(void* const* d_in, const int* in_sizes, int n_in,
                              void* d_out, int out_size, void* d_ws, size_t ws_size,
                              hipStream_t stream) {
    const float* x1 = (const float*)d_in[0];
    const float* x2 = (const float*)d_in[1];
    float* out = (float*)d_out;
    tp_kernel<<<BATCH, 256, 0, stream>>>(x1, x2, out);
}